// Round 6
// baseline (8984.976 us; speedup 1.0000x reference)
//
#include <hip/hip_runtime.h>
#include <math.h>

#define BN_EPS 1e-5f

__device__ __forceinline__ float mishf(float x){
  float sp = fmaxf(x, 0.f) + log1pf(__expf(-fabsf(x)));
  float e  = __expf(-2.f * sp);
  return x * ((1.f - e) / (1.f + e));
}

// monotone float<->uint encoding for atomicMax; all real floats encode > 0
__device__ __forceinline__ unsigned fenc(float f){
  unsigned u = __float_as_uint(f);
  return (u & 0x80000000u) ? ~u : (u | 0x80000000u);
}
__device__ __forceinline__ float fdec(unsigned e){
  unsigned u = (e & 0x80000000u) ? (e & 0x7fffffffu) : ~e;
  return __uint_as_float(u);
}

// stable top-10 insert: (value desc, index asc) == lax.top_k tie-break
__device__ __forceinline__ bool beats(float v, int i, float v2, int i2){
  return (v > v2) || (v == v2 && i < i2);
}
__device__ __forceinline__ void ins10(float (&lv)[10], int (&li)[10], float v, int i){
  if (!beats(v, i, lv[9], li[9])) return;
  #pragma unroll
  for (int p = 9; p >= 1; --p) {
    bool up   = beats(v, i, lv[p-1], li[p-1]);
    bool bp   = beats(v, i, lv[p],   li[p]);
    bool here = bp && !up;
    float nv = up ? lv[p-1] : (here ? v : lv[p]);
    int   ni = up ? li[p-1] : (here ? i : li[p]);
    lv[p] = nv; li[p] = ni;
  }
  if (beats(v, i, lv[0], li[0])) { lv[0] = v; li[0] = i; }
}

// ---------- diagnostic: encode a host-visible code into d_out[0] ----------
__global__ void k_diag(float* __restrict__ out, float v){
  out[0] = v;
}

// ---------- transpose x [B,3,N] -> xf [B*N,3] ----------
__global__ __launch_bounds__(256)
void k_cast(const float* __restrict__ x, float* __restrict__ xf){
  int i = blockIdx.x * 256 + threadIdx.x;      // 8*3*2048 = 49152
  int n = i & 2047, c = (i >> 11) % 3, b = i / (3 * 2048);
  xf[(size_t)(b * 2048 + n) * 3 + c] = x[i];
}

// ---------- zero glob ----------
__global__ __launch_bounds__(256)
void k_zero(unsigned* __restrict__ p){
  p[blockIdx.x * 256 + threadIdx.x] = 0u;      // 32 blocks -> 8192
}

// ---------- squared norm per point ----------
template<int C>
__global__ __launch_bounds__(256)
void k_norm(const float* __restrict__ src, int stride, int off,
            float* __restrict__ sq){
  int i = blockIdx.x * 256 + threadIdx.x;      // 16384
  const float* r = src + (size_t)i * stride + off;
  float s = 0.f;
  #pragma unroll
  for (int c = 0; c < C; ++c) s = fmaf(r[c], r[c], s);
  sq[i] = s;
}

// ---------- knn scan: one thread per point, wave-uniform row reads ----------
template<int C>
__global__ __launch_bounds__(256)
void k_knn(const float* __restrict__ src, int stride, int off,
           const float* __restrict__ sq, int* __restrict__ idxout){
  int gid = blockIdx.x * 256 + threadIdx.x;    // 16384
  int b = gid >> 11, n = gid & 2047;
  const float* base = src + (size_t)b * 2048 * stride + off;
  const float* sqb  = sq + b * 2048;
  float own[C];
  #pragma unroll
  for (int c = 0; c < C; ++c) own[c] = base[(size_t)n * stride + c];
  float sown = sqb[n];
  float lv[10]; int li[10];
  #pragma unroll
  for (int j = 0; j < 10; ++j){ lv[j] = -INFINITY; li[j] = 0x7fffffff; }
  for (int m = 0; m < 2048; ++m) {
    const float* row = base + (size_t)m * stride;
    float dot = 0.f;
    #pragma unroll
    for (int c = 0; c < C; ++c) dot = fmaf(own[c], row[c], dot);
    float key = 2.f * dot - sown - sqb[m];
    ins10(lv, li, key, m);
  }
  #pragma unroll
  for (int j = 0; j < 10; ++j) idxout[(size_t)gid * 10 + j] = li[j];
}

// ---------- edge conv stage: one block (64 threads) per point ----------
// conv1(2C->64)+BN+mish [-> conv2(64->64)+BN+mish] -> max over k -> cat col block
template<int C, bool HAS2>
__global__ __launch_bounds__(64)
void k_edgeconv(const float* __restrict__ src, int stride, int soff,
                const int* __restrict__ idx,
                const float* __restrict__ wa,   // [64][2C]
                const float* __restrict__ wb,   // [64][64] (HAS2)
                const float* __restrict__ g1, const float* __restrict__ b1,
                const float* __restrict__ m1, const float* __restrict__ v1,
                const float* __restrict__ g2, const float* __restrict__ b2,
                const float* __restrict__ m2, const float* __restrict__ v2,
                float* __restrict__ cat, int coff)
{
  __shared__ float ctr[64];
  __shared__ float nb[64];
  __shared__ float h1[10][64];
  const int t = threadIdx.x;                   // = output channel o
  const int p = blockIdx.x;                    // 16384 blocks
  const int batch = p >> 11;

  if (t < C) ctr[t] = src[(size_t)p * stride + soff + t];
  __syncthreads();

  float s1 = g1[t] / sqrtf(v1[t] + BN_EPS);
  float o1 = b1[t] - m1[t] * s1;

  // k-invariant: center contribution + (-ctr).wa_diff folded into base
  float basev = 0.f;
  #pragma unroll
  for (int c = 0; c < C; ++c)
    basev = fmaf(ctr[c], wa[t * 2 * C + C + c] , basev);
  #pragma unroll
  for (int c = 0; c < C; ++c)
    basev = fmaf(-ctr[c], wa[t * 2 * C + c], basev);

  float runmax = -INFINITY;
  for (int k = 0; k < 10; ++k) {
    int j = idx[p * 10 + k] & 2047;            // mask: fault-proof
    if (t < C) nb[t] = src[(size_t)(batch * 2048 + j) * stride + soff + t];
    __syncthreads();
    float acc = basev;
    #pragma unroll
    for (int c = 0; c < C; ++c)
      acc = fmaf(nb[c], wa[t * 2 * C + c], acc);
    float h = mishf(acc * s1 + o1);
    if (HAS2) h1[k][t] = h;
    else      runmax = fmaxf(runmax, h);
    __syncthreads();
  }

  if (HAS2) {
    __syncthreads();
    float s2 = g2[t] / sqrtf(v2[t] + BN_EPS);
    float o2 = b2[t] - m2[t] * s2;
    for (int k = 0; k < 10; ++k) {
      float acc = 0.f;
      #pragma unroll
      for (int c = 0; c < 64; ++c)
        acc = fmaf(h1[k][c], wb[t * 64 + c], acc);
      runmax = fmaxf(runmax, mishf(acc * s2 + o2));
    }
  }
  cat[(size_t)p * 192 + coff + t] = runmax;
}

// ---------- layer 6: glob[b][o] = max_p mish(bn(w6 . cat[p])) ----------
__global__ __launch_bounds__(256)
void k_conv6(const float* __restrict__ cat, const float* __restrict__ w6,
             const float* __restrict__ gg, const float* __restrict__ bb,
             const float* __restrict__ mn, const float* __restrict__ vv,
             unsigned* __restrict__ glob)
{
  int o  = blockIdx.x * 256 + threadIdx.x;     // 0..1023
  int p0 = blockIdx.y * 128;
  int b  = p0 >> 11;
  float s = gg[o] / sqrtf(vv[o] + BN_EPS);
  float f = bb[o] - mn[o] * s;
  float mx = -INFINITY;
  for (int p = p0; p < p0 + 128; ++p) {
    const float* cr = cat + (size_t)p * 192;
    float acc = 0.f;
    for (int c = 0; c < 192; ++c)
      acc = fmaf(cr[c], w6[(size_t)o * 192 + c], acc);
    mx = fmaxf(mx, mishf(acc * s + f));
  }
  atomicMax(&glob[b * 1024 + o], fenc(mx));
}

// ---------- t7[b][o] = w7[o, :1024] . glob[b] ----------
__global__ __launch_bounds__(256)
void k_t7(const unsigned* __restrict__ glob, const float* __restrict__ w7,
          float* __restrict__ t7){
  int i = blockIdx.x * 256 + threadIdx.x;      // 4096
  int b = i >> 9, o = i & 511;
  float acc = 0.f;
  for (int c = 0; c < 1024; ++c)
    acc = fmaf(w7[(size_t)o * 1216 + c], fdec(glob[b * 1024 + c]), acc);
  t7[i] = acc;
}

// ---------- layer 7: h7[p][o] = mish(bn(w7b . cat[p] + t7[b][o])) ----------
__global__ __launch_bounds__(256)
void k_conv7(const float* __restrict__ cat, const float* __restrict__ w7b,
             const float* __restrict__ t7,
             const float* __restrict__ gg, const float* __restrict__ bb,
             const float* __restrict__ mn, const float* __restrict__ vv,
             float* __restrict__ h7)
{
  int o  = blockIdx.x * 256 + threadIdx.x;     // 0..511
  int p0 = blockIdx.y * 128;
  int b  = p0 >> 11;
  float s = gg[o] / sqrtf(vv[o] + BN_EPS);
  float f = bb[o] - mn[o] * s;
  float bias = t7[b * 512 + o];
  for (int p = p0; p < p0 + 128; ++p) {
    const float* cr = cat + (size_t)p * 192;
    float acc = bias;
    for (int c = 0; c < 192; ++c)
      acc = fmaf(cr[c], w7b[(size_t)o * 1216 + c], acc);
    h7[(size_t)p * 512 + o] = mishf(acc * s + f);
  }
}

// ---------- layer 8: h8[p][o] = mish(bn(w8 . h7[p])) ----------
__global__ __launch_bounds__(256)
void k_conv8(const float* __restrict__ h7, const float* __restrict__ w8,
             const float* __restrict__ gg, const float* __restrict__ bb,
             const float* __restrict__ mn, const float* __restrict__ vv,
             float* __restrict__ h8)
{
  int o  = threadIdx.x;                        // 0..255
  int p0 = blockIdx.y * 64;
  float s = gg[o] / sqrtf(vv[o] + BN_EPS);
  float f = bb[o] - mn[o] * s;
  for (int p = p0; p < p0 + 64; ++p) {
    const float* hr = h7 + (size_t)p * 512;
    float acc = 0.f;
    for (int c = 0; c < 512; ++c)
      acc = fmaf(hr[c], w8[(size_t)o * 512 + c], acc);
    h8[(size_t)p * 256 + o] = mishf(acc * s + f);
  }
}

// ---------- final conv: block 256 = 4 points; LDS-staged h8 row ----------
__global__ __launch_bounds__(256)
void k_out(const float* __restrict__ h8, const float* __restrict__ w9,
           float* __restrict__ out)
{
  __shared__ float row[4][256];
  const int t = threadIdx.x;
  const int g = t >> 6, l = t & 63;
  const int p = blockIdx.x * 4 + g;            // 4096 blocks
  for (int c = l; c < 256; c += 64)
    row[g][c] = h8[(size_t)p * 256 + c];
  __syncthreads();
  if (l < 18) {
    float acc = 0.f;
    for (int c = 0; c < 256; ++c)
      acc = fmaf(row[g][c], w9[l * 256 + c], acc);
    int b = p >> 11, n = p & 2047;
    out[(size_t)b * 36864 + l * 2048 + n] = acc;
  }
}

extern "C" void kernel_launch(void* const* d_in, const int* in_sizes, int n_in,
                              void* d_out, int out_size, void* d_ws, size_t ws_size,
                              hipStream_t stream)
{
  // ---- workspace layout (fixed, 63,881,216 B; round-5 proved ws_size >= this) ----
  const size_t OFF_XF   = 0;                   //    196,608  [16384][3]
  const size_t OFF_SQ   = 196608;              //     65,536  [16384]
  const size_t OFF_IDX  = 262144;              //    655,360  [16384][10]
  const size_t OFF_CAT  = 917504;              // 12,582,912  [16384][192]
  const size_t OFF_GLOB = 13500416;            //     32,768  [8][1024]
  const size_t OFF_T7   = 13533184;            //     16,384  [8][512]
  const size_t OFF_H7   = 13549568;            // 33,554,432  [16384][512]
  const size_t OFF_H8   = 47104000;            // 16,777,216  [16384][256]
  const size_t NEED     = 63881216;

  // ---- guards (all passed in round 5; kept as cheap insurance) ----
  static const int EXP[26] = {
    49152, 384, 4096, 8192, 4096, 8192, 196608, 622592, 131072, 4608,
    320, 320, 320, 320, 1024, 1024, 1024, 1024,
    512, 512, 512, 512, 256, 256, 256, 256 };
  if (n_in < 26) { k_diag<<<1,1,0,stream>>>((float*)d_out, 16384.f); return; }
  for (int i = 0; i < 26; ++i)
    if (in_sizes[i] != EXP[i]) {
      k_diag<<<1,1,0,stream>>>((float*)d_out, 4096.f + 128.f * i); return;
    }
  if (out_size != 294912) { k_diag<<<1,1,0,stream>>>((float*)d_out, 20480.f); return; }
  if (ws_size < NEED) {
    k_diag<<<1,1,0,stream>>>((float*)d_out, 24576.f + (float)(ws_size >> 20)); return;
  }

  // ---- inputs are FLOAT32 (reference dtypes; round-5 NaN chain proved bf16 read wrong) ----
  const float* x  = (const float*)d_in[0];
  const float* w1 = (const float*)d_in[1];
  const float* w2 = (const float*)d_in[2];
  const float* w3 = (const float*)d_in[3];
  const float* w4 = (const float*)d_in[4];
  const float* w5 = (const float*)d_in[5];
  const float* w6 = (const float*)d_in[6];
  const float* w7 = (const float*)d_in[7];
  const float* w8 = (const float*)d_in[8];
  const float* w9 = (const float*)d_in[9];
  const float* g15 = (const float*)d_in[10];
  const float* b15 = (const float*)d_in[11];
  const float* m15 = (const float*)d_in[12];
  const float* v15 = (const float*)d_in[13];
  const float* g6 = (const float*)d_in[14];
  const float* b6 = (const float*)d_in[15];
  const float* m6 = (const float*)d_in[16];
  const float* v6 = (const float*)d_in[17];
  const float* g7 = (const float*)d_in[18];
  const float* b7 = (const float*)d_in[19];
  const float* m7 = (const float*)d_in[20];
  const float* v7 = (const float*)d_in[21];
  const float* g8 = (const float*)d_in[22];
  const float* b8 = (const float*)d_in[23];
  const float* m8 = (const float*)d_in[24];
  const float* v8 = (const float*)d_in[25];

  char* ws = (char*)d_ws;
  float*    xf   = (float*)(ws + OFF_XF);
  float*    sq   = (float*)(ws + OFF_SQ);
  int*      idx  = (int*)(ws + OFF_IDX);
  float*    cat  = (float*)(ws + OFF_CAT);
  unsigned* glob = (unsigned*)(ws + OFF_GLOB);
  float*    t7   = (float*)(ws + OFF_T7);
  float*    h7   = (float*)(ws + OFF_H7);
  float*    h8   = (float*)(ws + OFF_H8);

  k_cast<<<192, 256, 0, stream>>>(x, xf);

  // ---- stage 1: x(3) -> conv(6->64)+conv(64->64) -> max_k -> cat[:,0:64] ----
  k_norm<3><<<64, 256, 0, stream>>>(xf, 3, 0, sq);
  k_knn<3><<<64, 256, 0, stream>>>(xf, 3, 0, sq, idx);
  k_edgeconv<3, true><<<16384, 64, 0, stream>>>(
      xf, 3, 0, idx, w1, w2,
      g15 + 0,  b15 + 0,  m15 + 0,  v15 + 0,
      g15 + 64, b15 + 64, m15 + 64, v15 + 64,
      cat, 0);

  // ---- stage 2 ----
  k_norm<64><<<64, 256, 0, stream>>>(cat, 192, 0, sq);
  k_knn<64><<<64, 256, 0, stream>>>(cat, 192, 0, sq, idx);
  k_edgeconv<64, true><<<16384, 64, 0, stream>>>(
      cat, 192, 0, idx, w3, w4,
      g15 + 128, b15 + 128, m15 + 128, v15 + 128,
      g15 + 192, b15 + 192, m15 + 192, v15 + 192,
      cat, 64);

  // ---- stage 3 ----
  k_norm<64><<<64, 256, 0, stream>>>(cat, 192, 64, sq);
  k_knn<64><<<64, 256, 0, stream>>>(cat, 192, 64, sq, idx);
  k_edgeconv<64, false><<<16384, 64, 0, stream>>>(
      cat, 192, 64, idx, w5, nullptr,
      g15 + 256, b15 + 256, m15 + 256, v15 + 256,
      nullptr, nullptr, nullptr, nullptr,
      cat, 128);

  // ---- layer 6 -> glob ----
  k_zero<<<32, 256, 0, stream>>>(glob);
  dim3 g6g(4, 128);
  k_conv6<<<g6g, 256, 0, stream>>>(cat, w6, g6, b6, m6, v6, glob);

  // ---- t7 = w7[:, :1024] . glob ----
  k_t7<<<16, 256, 0, stream>>>(glob, w7, t7);

  // ---- layer 7 ----
  dim3 g7g(2, 128);
  k_conv7<<<g7g, 256, 0, stream>>>(cat, w7 + 1024, t7, g7, b7, m7, v7, h7);

  // ---- layer 8 ----
  dim3 g8g(1, 256);
  k_conv8<<<g8g, 256, 0, stream>>>(h7, w8, g8, b8, m8, v8, h8);

  // ---- output ----
  k_out<<<4096, 256, 0, stream>>>(h8, w9, (float*)d_out);
}

// Round 7
// 1791.102 us; speedup vs baseline: 5.0165x; 5.0165x over previous
//
#include <hip/hip_runtime.h>
#include <math.h>

#define BN_EPS 1e-5f

__device__ __forceinline__ float mishf(float x){
  float sp = fmaxf(x, 0.f) + log1pf(__expf(-fabsf(x)));
  float e  = __expf(-2.f * sp);
  return x * ((1.f - e) / (1.f + e));
}

// monotone float<->uint encoding for atomicMax; all real floats encode > 0
__device__ __forceinline__ unsigned fenc(float f){
  unsigned u = __float_as_uint(f);
  return (u & 0x80000000u) ? ~u : (u | 0x80000000u);
}
__device__ __forceinline__ float fdec(unsigned e){
  unsigned u = (e & 0x80000000u) ? (e & 0x7fffffffu) : ~e;
  return __uint_as_float(u);
}

// stable top-10 insert: (value desc, index asc) == lax.top_k tie-break
__device__ __forceinline__ bool beats(float v, int i, float v2, int i2){
  return (v > v2) || (v == v2 && i < i2);
}
__device__ __forceinline__ void ins10(float (&lv)[10], int (&li)[10], float v, int i){
  if (!beats(v, i, lv[9], li[9])) return;
  #pragma unroll
  for (int p = 9; p >= 1; --p) {
    bool up   = beats(v, i, lv[p-1], li[p-1]);
    bool bp   = beats(v, i, lv[p],   li[p]);
    bool here = bp && !up;
    float nv = up ? lv[p-1] : (here ? v : lv[p]);
    int   ni = up ? li[p-1] : (here ? i : li[p]);
    lv[p] = nv; li[p] = ni;
  }
  if (beats(v, i, lv[0], li[0])) { lv[0] = v; li[0] = i; }
}

__global__ void k_diag(float* __restrict__ out, float v){ out[0] = v; }

// ---------- transpose x [B,3,N] -> xf [B*N,3] ----------
__global__ __launch_bounds__(256)
void k_cast(const float* __restrict__ x, float* __restrict__ xf){
  int i = blockIdx.x * 256 + threadIdx.x;      // 49152
  int n = i & 2047, c = (i >> 11) % 3, b = i / (3 * 2048);
  xf[(size_t)(b * 2048 + n) * 3 + c] = x[i];
}

__global__ __launch_bounds__(256)
void k_zero(unsigned* __restrict__ p){
  p[blockIdx.x * 256 + threadIdx.x] = 0u;      // 32 blocks -> 8192
}

// ---------- knn: 32 points/block, 8 chunk-threads/point, LDS m-tiles of 128 ----------
template<int C>
__global__ __launch_bounds__(256)
void k_knn(const float* __restrict__ src, int stride, int off, int* __restrict__ idxout){
  constexpr int PAD = (C == 3) ? 4 : 68;
  __shared__ float pts[128 * PAD];
  __shared__ float ss[128];
  __shared__ float mlv[32 * 8 * 10];
  __shared__ int   mli[32 * 8 * 10];
  const int t  = threadIdx.x;
  const int b  = blockIdx.x >> 6;              // 64 blocks per batch
  const int p0 = (blockIdx.x & 63) * 32;
  const int p  = t >> 3, ch = t & 7;
  const int n  = p0 + p;
  const float* srow = src + (size_t)(b * 2048 + n) * stride + off;
  float own[C];
  #pragma unroll
  for (int c = 0; c < C; ++c) own[c] = srow[c];
  float sown = 0.f;
  #pragma unroll
  for (int c = 0; c < C; ++c) sown = fmaf(own[c], own[c], sown);
  float lv[10]; int li[10];
  #pragma unroll
  for (int j = 0; j < 10; ++j){ lv[j] = -INFINITY; li[j] = 0x7fffffff; }

  for (int m0 = 0; m0 < 2048; m0 += 128) {
    __syncthreads();
    for (int i = t; i < 128 * C; i += 256) {
      int mm = i / C, c = i % C;
      pts[mm * PAD + c] = src[(size_t)(b * 2048 + m0 + mm) * stride + off + c];
    }
    __syncthreads();
    if (t < 128) {
      float s2 = 0.f;
      #pragma unroll
      for (int c = 0; c < C; ++c) s2 = fmaf(pts[t * PAD + c], pts[t * PAD + c], s2);
      ss[t] = s2;
    }
    __syncthreads();
    for (int mm = ch; mm < 128; mm += 8) {
      float dot = 0.f;
      #pragma unroll
      for (int c = 0; c < C; ++c) dot = fmaf(own[c], pts[mm * PAD + c], dot);
      float key = 2.f * dot - sown - ss[mm];   // self -> exactly 0
      ins10(lv, li, key, m0 + mm);
    }
  }
  __syncthreads();
  #pragma unroll
  for (int j = 0; j < 10; ++j) { mlv[t * 10 + j] = lv[j]; mli[t * 10 + j] = li[j]; }
  __syncthreads();
  if (t < 32) {
    float fv[10]; int fi[10];
    #pragma unroll
    for (int j = 0; j < 10; ++j){ fv[j] = -INFINITY; fi[j] = 0x7fffffff; }
    for (int c2 = 0; c2 < 8; ++c2)
      for (int j = 0; j < 10; ++j)
        ins10(fv, fi, mlv[(t * 8 + c2) * 10 + j], mli[(t * 8 + c2) * 10 + j]);
    #pragma unroll
    for (int j = 0; j < 10; ++j)
      idxout[(size_t)(b * 2048 + p0 + t) * 10 + j] = fi[j];
  }
}

// ---------- fused stage: edge-gather -> conv1+BN+mish [-> conv2+BN+mish] -> max_k ----------
// block = 8 points = 80 edges; tx in [0,16) -> 5 edges, ty in [0,16) -> 4 outs.
template<int C, bool HAS2>
__global__ __launch_bounds__(256)
void k_stage(const float* __restrict__ src, int stride, int soff,
             const int* __restrict__ idx,
             const float* __restrict__ wa,    // [64][2C]
             const float* __restrict__ wb,    // [64][64] (HAS2)
             const float* __restrict__ g1, const float* __restrict__ b1,
             const float* __restrict__ m1, const float* __restrict__ v1,
             const float* __restrict__ g2, const float* __restrict__ b2,
             const float* __restrict__ m2, const float* __restrict__ v2,
             float* __restrict__ cat, int coff)
{
  constexpr int K1 = 2 * C;
  __shared__ float As[16][85];                 // [k][edge], odd-ish stride
  __shared__ float Bs[16][68];                 // [k][out]
  __shared__ float As2[HAS2 ? 64 : 1][HAS2 ? 85 : 1];
  __shared__ float mx2[16][68];
  const int t  = threadIdx.x;
  const int tx = t & 15, ty = t >> 4;
  const int p0 = blockIdx.x * 8;               // 2048 blocks
  const int batch = p0 >> 11;
  const int e0 = p0 * 10;
  float acc[5][4] = {};

  // ---- conv1: K1 -> 64 ----
  for (int k0 = 0; k0 < K1; k0 += 16) {
    for (int i = t; i < 1280; i += 256) {      // 80 edges x 16 k
      int m = i >> 4, k = i & 15;
      int gk = k0 + k;
      float v = 0.f;
      if (gk < K1) {
        int q  = m / 10;
        int pt = p0 + q;
        int j  = idx[e0 + m] & 2047;           // masked: fault-proof
        const float* cr = src + (size_t)pt * stride + soff;
        const float* nr = src + (size_t)(batch * 2048 + j) * stride + soff;
        v = (gk < C) ? (nr[gk] - cr[gk]) : cr[gk - C];
      }
      As[k][m] = v;
    }
    for (int i = t; i < 1024; i += 256) {      // 64 outs x 16 k
      int n = i >> 4, k = i & 15;
      int gk = k0 + k;
      Bs[k][n] = (gk < K1) ? wa[n * K1 + gk] : 0.f;
    }
    __syncthreads();
    #pragma unroll
    for (int k = 0; k < 16; ++k) {
      float bv[4];
      #pragma unroll
      for (int j = 0; j < 4; ++j) bv[j] = Bs[k][ty * 4 + j];
      #pragma unroll
      for (int i2 = 0; i2 < 5; ++i2) {
        float a = As[k][tx * 5 + i2];
        #pragma unroll
        for (int j = 0; j < 4; ++j) acc[i2][j] = fmaf(a, bv[j], acc[i2][j]);
      }
    }
    __syncthreads();
  }

  float sc[4], of[4];
  #pragma unroll
  for (int j = 0; j < 4; ++j) {
    int nn = ty * 4 + j;
    float s = g1[nn] / sqrtf(v1[nn] + BN_EPS);
    sc[j] = s;
    of[j] = b1[nn] - m1[nn] * s;
  }

  float mxv[4] = {-INFINITY, -INFINITY, -INFINITY, -INFINITY};

  if constexpr (HAS2) {
    #pragma unroll
    for (int i2 = 0; i2 < 5; ++i2)
      #pragma unroll
      for (int j = 0; j < 4; ++j)
        As2[ty * 4 + j][tx * 5 + i2] = mishf(acc[i2][j] * sc[j] + of[j]);
    __syncthreads();

    // ---- conv2: 64 -> 64 ----
    float acc2[5][4] = {};
    for (int k0 = 0; k0 < 64; k0 += 16) {
      for (int i = t; i < 1024; i += 256) {
        int n = i >> 4, k = i & 15;
        Bs[k][n] = wb[n * 64 + k0 + k];
      }
      __syncthreads();
      #pragma unroll
      for (int k = 0; k < 16; ++k) {
        float bv[4];
        #pragma unroll
        for (int j = 0; j < 4; ++j) bv[j] = Bs[k][ty * 4 + j];
        #pragma unroll
        for (int i2 = 0; i2 < 5; ++i2) {
          float a = As2[k0 + k][tx * 5 + i2];
          #pragma unroll
          for (int j = 0; j < 4; ++j) acc2[i2][j] = fmaf(a, bv[j], acc2[i2][j]);
        }
      }
      __syncthreads();
    }
    float sc2[4], of2[4];
    #pragma unroll
    for (int j = 0; j < 4; ++j) {
      int nn = ty * 4 + j;
      float s = g2[nn] / sqrtf(v2[nn] + BN_EPS);
      sc2[j] = s;
      of2[j] = b2[nn] - m2[nn] * s;
    }
    #pragma unroll
    for (int i2 = 0; i2 < 5; ++i2)
      #pragma unroll
      for (int j = 0; j < 4; ++j)
        mxv[j] = fmaxf(mxv[j], mishf(acc2[i2][j] * sc2[j] + of2[j]));
  } else {
    #pragma unroll
    for (int i2 = 0; i2 < 5; ++i2)
      #pragma unroll
      for (int j = 0; j < 4; ++j)
        mxv[j] = fmaxf(mxv[j], mishf(acc[i2][j] * sc[j] + of[j]));
  }

  // per-thread (5 edges) partial max -> combine halves -> cat
  #pragma unroll
  for (int j = 0; j < 4; ++j) mx2[tx][ty * 4 + j] = mxv[j];
  __syncthreads();
  for (int i = t; i < 512; i += 256) {         // 8 points x 64 cols
    int p = i >> 6, o = i & 63;
    float v = fmaxf(mx2[2 * p][o], mx2[2 * p + 1][o]);
    cat[(size_t)(p0 + p) * 192 + coff + o] = v;
  }
}

// ---------- tiled fp32 GEMM: C[M,*] = A[M,K] * W[N,K]^T, BM=BN=64, BK=16 ----------
#define EP_BNMISH      0
#define EP_MAXGLOB     1
#define EP_BIAS_BNMISH 2

template<int EPI>
__global__ __launch_bounds__(256)
void k_gemm(const float* __restrict__ A, int lda,
            const float* __restrict__ W, int ldw, int K,
            const float* __restrict__ gg, const float* __restrict__ bb,
            const float* __restrict__ mn, const float* __restrict__ vv,
            const float* __restrict__ bias,
            float* __restrict__ out, int ldo,
            unsigned* __restrict__ glob)
{
  __shared__ float As[16][68];
  __shared__ float Bs[16][68];
  const int t  = threadIdx.x;
  const int tx = t & 15, ty = t >> 4;
  const int m0 = blockIdx.x * 64, n0 = blockIdx.y * 64;
  float acc[4][4] = {};

  for (int k0 = 0; k0 < K; k0 += 16) {
    for (int i = t; i < 1024; i += 256) {
      int m = i >> 4, k = i & 15;
      As[k][m] = A[(size_t)(m0 + m) * lda + k0 + k];
    }
    for (int i = t; i < 1024; i += 256) {
      int nn = i >> 4, k = i & 15;
      Bs[k][nn] = W[(size_t)(n0 + nn) * ldw + k0 + k];
    }
    __syncthreads();
    #pragma unroll
    for (int k = 0; k < 16; ++k) {
      float am[4], bm[4];
      #pragma unroll
      for (int q = 0; q < 4; ++q) { am[q] = As[k][tx * 4 + q]; bm[q] = Bs[k][ty * 4 + q]; }
      #pragma unroll
      for (int i2 = 0; i2 < 4; ++i2)
        #pragma unroll
        for (int j = 0; j < 4; ++j)
          acc[i2][j] = fmaf(am[i2], bm[j], acc[i2][j]);
    }
    __syncthreads();
  }

  float sc[4], of[4];
  #pragma unroll
  for (int j = 0; j < 4; ++j) {
    int nn = n0 + ty * 4 + j;
    float s = gg[nn] / sqrtf(vv[nn] + BN_EPS);
    sc[j] = s;
    of[j] = bb[nn] - mn[nn] * s;
  }

  if (EPI == EP_MAXGLOB) {
    float mx[4] = {-INFINITY, -INFINITY, -INFINITY, -INFINITY};
    #pragma unroll
    for (int i2 = 0; i2 < 4; ++i2)
      #pragma unroll
      for (int j = 0; j < 4; ++j)
        mx[j] = fmaxf(mx[j], mishf(acc[i2][j] * sc[j] + of[j]));
    __syncthreads();
    float* red = &As[0][0];                    // 1024 floats fit
    #pragma unroll
    for (int j = 0; j < 4; ++j) red[(ty * 4 + j) * 16 + tx] = mx[j];
    __syncthreads();
    if (t < 64) {
      float v = red[t * 16];
      #pragma unroll
      for (int r = 1; r < 16; ++r) v = fmaxf(v, red[t * 16 + r]);
      atomicMax(&glob[(m0 >> 11) * 1024 + n0 + t], fenc(v));
    }
  } else {
    #pragma unroll
    for (int i2 = 0; i2 < 4; ++i2) {
      int m = m0 + tx * 4 + i2;
      #pragma unroll
      for (int j = 0; j < 4; ++j) {
        int nn = n0 + ty * 4 + j;
        float v = acc[i2][j];
        if (EPI == EP_BIAS_BNMISH) v += bias[(m >> 11) * 512 + nn];
        out[(size_t)m * ldo + nn] = mishf(v * sc[j] + of[j]);
      }
    }
  }
}

// ---------- t7[b][o] = w7[o, :1024] . glob[b] ----------
__global__ __launch_bounds__(256)
void k_t7(const unsigned* __restrict__ glob, const float* __restrict__ w7,
          float* __restrict__ t7){
  int i = blockIdx.x * 256 + threadIdx.x;      // 4096
  int b = i >> 9, o = i & 511;
  float acc = 0.f;
  for (int c = 0; c < 1024; ++c)
    acc = fmaf(w7[(size_t)o * 1216 + c], fdec(glob[b * 1024 + c]), acc);
  t7[i] = acc;
}

// ---------- final conv: block 256 = 4 points; LDS-staged h8 row ----------
__global__ __launch_bounds__(256)
void k_out(const float* __restrict__ h8, const float* __restrict__ w9,
           float* __restrict__ out)
{
  __shared__ float row[4][256];
  const int t = threadIdx.x;
  const int g = t >> 6, l = t & 63;
  const int p = blockIdx.x * 4 + g;            // 4096 blocks
  for (int c = l; c < 256; c += 64)
    row[g][c] = h8[(size_t)p * 256 + c];
  __syncthreads();
  if (l < 18) {
    float acc = 0.f;
    for (int c = 0; c < 256; ++c)
      acc = fmaf(row[g][c], w9[l * 256 + c], acc);
    int b = p >> 11, n = p & 2047;
    out[(size_t)b * 36864 + l * 2048 + n] = acc;
  }
}

extern "C" void kernel_launch(void* const* d_in, const int* in_sizes, int n_in,
                              void* d_out, int out_size, void* d_ws, size_t ws_size,
                              hipStream_t stream)
{
  // ---- workspace layout (63,881,216 B; round-5/6 proved ws_size >= this) ----
  const size_t OFF_XF   = 0;                   //    196,608  [16384][3]
  const size_t OFF_IDX  = 262144;              //    655,360  [16384][10]
  const size_t OFF_CAT  = 917504;              // 12,582,912  [16384][192]
  const size_t OFF_GLOB = 13500416;            //     32,768  [8][1024]
  const size_t OFF_T7   = 13533184;            //     16,384  [8][512]
  const size_t OFF_H7   = 13549568;            // 33,554,432  [16384][512]
  const size_t OFF_H8   = 47104000;            // 16,777,216  [16384][256]
  const size_t NEED     = 63881216;

  static const int EXP[26] = {
    49152, 384, 4096, 8192, 4096, 8192, 196608, 622592, 131072, 4608,
    320, 320, 320, 320, 1024, 1024, 1024, 1024,
    512, 512, 512, 512, 256, 256, 256, 256 };
  if (n_in < 26) { k_diag<<<1,1,0,stream>>>((float*)d_out, 16384.f); return; }
  for (int i = 0; i < 26; ++i)
    if (in_sizes[i] != EXP[i]) {
      k_diag<<<1,1,0,stream>>>((float*)d_out, 4096.f + 128.f * i); return;
    }
  if (out_size != 294912) { k_diag<<<1,1,0,stream>>>((float*)d_out, 20480.f); return; }
  if (ws_size < NEED) {
    k_diag<<<1,1,0,stream>>>((float*)d_out, 24576.f + (float)(ws_size >> 20)); return;
  }

  const float* x  = (const float*)d_in[0];
  const float* w1 = (const float*)d_in[1];
  const float* w2 = (const float*)d_in[2];
  const float* w3 = (const float*)d_in[3];
  const float* w4 = (const float*)d_in[4];
  const float* w5 = (const float*)d_in[5];
  const float* w6 = (const float*)d_in[6];
  const float* w7 = (const float*)d_in[7];
  const float* w8 = (const float*)d_in[8];
  const float* w9 = (const float*)d_in[9];
  const float* g15 = (const float*)d_in[10];
  const float* b15 = (const float*)d_in[11];
  const float* m15 = (const float*)d_in[12];
  const float* v15 = (const float*)d_in[13];
  const float* g6 = (const float*)d_in[14];
  const float* b6 = (const float*)d_in[15];
  const float* m6 = (const float*)d_in[16];
  const float* v6 = (const float*)d_in[17];
  const float* g7 = (const float*)d_in[18];
  const float* b7 = (const float*)d_in[19];
  const float* m7 = (const float*)d_in[20];
  const float* v7 = (const float*)d_in[21];
  const float* g8 = (const float*)d_in[22];
  const float* b8 = (const float*)d_in[23];
  const float* m8 = (const float*)d_in[24];
  const float* v8 = (const float*)d_in[25];

  char* ws = (char*)d_ws;
  float*    xf   = (float*)(ws + OFF_XF);
  int*      idx  = (int*)(ws + OFF_IDX);
  float*    cat  = (float*)(ws + OFF_CAT);
  unsigned* glob = (unsigned*)(ws + OFF_GLOB);
  float*    t7   = (float*)(ws + OFF_T7);
  float*    h7   = (float*)(ws + OFF_H7);
  float*    h8   = (float*)(ws + OFF_H8);

  k_cast<<<192, 256, 0, stream>>>(x, xf);

  // ---- stage 1: x(3) -> conv(6->64)+conv(64->64) -> max_k -> cat[:,0:64] ----
  k_knn<3><<<512, 256, 0, stream>>>(xf, 3, 0, idx);
  k_stage<3, true><<<2048, 256, 0, stream>>>(
      xf, 3, 0, idx, w1, w2,
      g15 + 0,  b15 + 0,  m15 + 0,  v15 + 0,
      g15 + 64, b15 + 64, m15 + 64, v15 + 64,
      cat, 0);

  // ---- stage 2 ----
  k_knn<64><<<512, 256, 0, stream>>>(cat, 192, 0, idx);
  k_stage<64, true><<<2048, 256, 0, stream>>>(
      cat, 192, 0, idx, w3, w4,
      g15 + 128, b15 + 128, m15 + 128, v15 + 128,
      g15 + 192, b15 + 192, m15 + 192, v15 + 192,
      cat, 64);

  // ---- stage 3 ----
  k_knn<64><<<512, 256, 0, stream>>>(cat, 192, 64, idx);
  k_stage<64, false><<<2048, 256, 0, stream>>>(
      cat, 192, 64, idx, w5, nullptr,
      g15 + 256, b15 + 256, m15 + 256, v15 + 256,
      nullptr, nullptr, nullptr, nullptr,
      cat, 128);

  // ---- layer 6 -> glob (fused max over points) ----
  k_zero<<<32, 256, 0, stream>>>(glob);
  dim3 g6g(256, 16);
  k_gemm<EP_MAXGLOB><<<g6g, 256, 0, stream>>>(
      cat, 192, w6, 192, 192, g6, b6, m6, v6, nullptr, nullptr, 0, glob);

  // ---- t7 = w7[:, :1024] . glob ----
  k_t7<<<16, 256, 0, stream>>>(glob, w7, t7);

  // ---- layer 7: cat-part GEMM + per-batch t7 bias ----
  dim3 g7g(256, 8);
  k_gemm<EP_BIAS_BNMISH><<<g7g, 256, 0, stream>>>(
      cat, 192, w7 + 1024, 1216, 192, g7, b7, m7, v7, t7, h7, 512, nullptr);

  // ---- layer 8 ----
  dim3 g8g(256, 4);
  k_gemm<EP_BNMISH><<<g8g, 256, 0, stream>>>(
      h7, 512, w8, 512, 512, g8, b8, m8, v8, nullptr, h8, 256, nullptr);

  // ---- output ----
  k_out<<<4096, 256, 0, stream>>>(h8, w9, (float*)d_out);
}